// Round 1
// baseline (995.518 us; speedup 1.0000x reference)
//
#include <hip/hip_runtime.h>
#include <stdint.h>

#define NUM_EXPERTS 16
#define TOP_K 2
#define HIDDEN 1024
#define INTER 2048
#define NUM_TOKENS 4096
#define CAPACITY 768
#define NFLAT (NUM_TOKENS*TOP_K)

typedef __attribute__((ext_vector_type(4))) float f32x4;
typedef __attribute__((ext_vector_type(8))) short s16x8;

static __device__ __forceinline__ unsigned short f2bf(float f){
  union { float f; unsigned int u; } v; v.f = f;
  unsigned int r = (v.u + 0x7fffu + ((v.u >> 16) & 1u)) >> 16;
  return (unsigned short)r;
}
static __device__ __forceinline__ float bf2f(unsigned short s){
  union { unsigned int u; float f; } v; v.u = ((unsigned int)s) << 16;
  return v.f;
}

// ---------------------------------------------------------------- routing
// scales = top2 softmax probs renormalized by their sum -> softmax denom
// cancels: s1 = 1/(1+exp(l2-l1)), s2 = 1-s1.
__global__ void route_topk(const float* __restrict__ logits,
                           int* __restrict__ sel, float* __restrict__ scl){
  int t = blockIdx.x*blockDim.x + threadIdx.x;
  if(t >= NUM_TOKENS) return;
  const float* L = logits + (size_t)t*NUM_EXPERTS;
  float l[NUM_EXPERTS];
  #pragma unroll
  for(int j=0;j<NUM_EXPERTS;j+=4){
    float4 v = *(const float4*)(L + j);
    l[j]=v.x; l[j+1]=v.y; l[j+2]=v.z; l[j+3]=v.w;
  }
  int i1 = 0; float m1 = l[0];
  #pragma unroll
  for(int j=1;j<NUM_EXPERTS;j++) if(l[j] > m1){ m1=l[j]; i1=j; }
  int i2 = -1; float m2 = -1e30f;
  #pragma unroll
  for(int j=0;j<NUM_EXPERTS;j++) if(j != i1 && l[j] > m2){ m2=l[j]; i2=j; }
  float e  = __expf(m2 - m1);
  float s1 = 1.f/(1.f + e);
  float s2 = e*s1;
  sel[TOP_K*t]   = i1; sel[TOP_K*t+1] = i2;
  scl[TOP_K*t]   = s1; scl[TOP_K*t+1] = s2;
}

// Exact token-order positions per expert (matches reference cumsum order so
// capacity drops, if any, hit the same entries). One block per expert.
__global__ void assign_pos(const int* __restrict__ sel,
                           int* __restrict__ pos, int* __restrict__ cnt){
  const int e = blockIdx.x;
  const int tid = threadIdx.x;
  const int lane = tid & 63, w = tid >> 6;
  __shared__ int wsum[4];
  __shared__ int carry;
  if(tid == 0) carry = 0;
  __syncthreads();
  for(int c = 0; c < NFLAT; c += 256){
    int i = c + tid;                       // NFLAT % 256 == 0
    bool flag = (sel[i] == e);
    unsigned long long mask = __ballot(flag);
    int lp   = __popcll(mask & ((1ull << lane) - 1ull));
    int wtot = __popcll(mask);
    if(lane == 0) wsum[w] = wtot;
    __syncthreads();
    int base = carry;
    int off = base;
    for(int q=0;q<w;q++) off += wsum[q];
    int tot = wsum[0] + wsum[1] + wsum[2] + wsum[3];
    if(flag) pos[i] = off + lp;
    __syncthreads();
    if(tid == 0) carry = base + tot;
  }
  if(tid == 0) cnt[e] = (carry < CAPACITY) ? carry : CAPACITY;
}

// One wave per (token,k) entry: fp32 hidden row -> bf16 row in Abuf[e][pos].
__global__ void scatter_rows(const float* __restrict__ hs,
                             const int* __restrict__ sel, const int* __restrict__ pos,
                             unsigned short* __restrict__ Abuf){
  int i = blockIdx.x*(blockDim.x>>6) + (threadIdx.x>>6);
  int lane = threadIdx.x & 63;
  if(i >= NFLAT) return;
  int p = pos[i];
  if(p >= CAPACITY) return;                 // dropped entry: contributes zero
  int e = sel[i];
  int tok = i >> 1;                         // i = tok*TOP_K + k
  const float4* src = (const float4*)(hs + (size_t)tok*HIDDEN);
  unsigned short* dst = Abuf + ((size_t)e*CAPACITY + p)*HIDDEN;
  #pragma unroll
  for(int c=0;c<4;c++){
    float4 v = src[c*64 + lane];
    ushort4 o; o.x=f2bf(v.x); o.y=f2bf(v.y); o.z=f2bf(v.z); o.w=f2bf(v.w);
    *(ushort4*)(dst + (size_t)(c*64 + lane)*4) = o;
  }
}

// ---------------------------------------------------------------- GEMM
// C[s,n] = sum_k A[s,k] * W[n,k]   (W is fp32 "B^T" layout, rows of length ldw)
// DUAL: also compute with W rows offset by INTER (g1 half) and fuse SwiGLU.
// 128x128 tile, BK=64, 4 waves (2x2), 16x16x32 bf16 MFMA.
// LDS XOR-swizzle (byte ^= (row&7)<<4); A staged via global_load_lds with
// pre-swizzled per-lane source addresses (linear LDS dest), B reg-staged
// with inline fp32->bf16 convert and swizzled ds_write.
template<int DUAL>
__global__ __launch_bounds__(256,2) void moe_gemm(
    const unsigned short* __restrict__ Abase, int lda,
    const float* __restrict__ Wbase, int ldw, int nW,
    unsigned short* __restrict__ Obase, int ldo,
    const int* __restrict__ cnts, int K)
{
  extern __shared__ char smem[];
  char* sAc  = smem;            // 16 KB  [128][64] bf16, swizzled
  char* sBc  = smem + 16384;    // 16 KB
  char* sB2c = smem + 32768;    // 16 KB (DUAL only)

  const int e   = blockIdx.z;
  const int cnt = cnts[e];
  const int m0  = blockIdx.y * 128;
  if(m0 >= cnt) return;
  const int n0  = blockIdx.x * 128;

  const int tid  = threadIdx.x;
  const int lane = tid & 63;
  const int w    = tid >> 6;
  const int wm   = w >> 1, wn = w & 1;

  const unsigned short* Aexp = Abase + (size_t)e*CAPACITY*lda;
  const float* W0 = Wbase + (size_t)e*nW*ldw;

  f32x4 acc[4][4];
  f32x4 acc2[4][4];
  #pragma unroll
  for(int a=0;a<4;a++)
    #pragma unroll
    for(int b=0;b<4;b++){ acc[a][b]=(f32x4)(0.f); acc2[a][b]=(f32x4)(0.f); }

  // A-stage lane constants: 8 rows per 1KB glld instr, source chunk pre-swizzled
  const int ar = lane >> 3;            // row within 8-row group
  const int ac = (lane & 7) ^ ar;      // swizzled 16B-chunk index
  // B-stage constants: 16 threads/row, 4 f32 each
  const int brr = tid >> 4;
  const int bcc = tid & 15;

  for(int k0 = 0; k0 < K; k0 += 64){
    // --- stage A (bf16 ws -> LDS via async DMA)
    #pragma unroll
    for(int q=0;q<4;q++){
      int rowbase = w*32 + q*8;
      const unsigned short* g = Aexp + (size_t)(m0 + rowbase + ar)*lda + k0 + ac*8;
      __builtin_amdgcn_global_load_lds(
          (const __attribute__((address_space(1))) void*)g,
          (__attribute__((address_space(3))) void*)(sAc + rowbase*128),
          16, 0, 0);
    }
    // --- stage B (fp32 global -> cvt -> swizzled LDS)
    #pragma unroll
    for(int j=0;j<8;j++){
      int row = j*16 + brr;
      const float* gp = W0 + (size_t)(n0 + row)*ldw + k0 + bcc*4;
      float4 v = *(const float4*)gp;
      ushort4 o; o.x=f2bf(v.x); o.y=f2bf(v.y); o.z=f2bf(v.z); o.w=f2bf(v.w);
      int sb = row*128 + ((bcc*8) ^ ((row & 7) << 4));
      *(ushort4*)(sBc + sb) = o;
      if(DUAL){
        float4 v2 = *(const float4*)(gp + (size_t)INTER*ldw);
        ushort4 o2; o2.x=f2bf(v2.x); o2.y=f2bf(v2.y); o2.z=f2bf(v2.z); o2.w=f2bf(v2.w);
        *(ushort4*)(sB2c + sb) = o2;
      }
    }
    __syncthreads();   // compiler drains vmcnt(0) lgkmcnt(0) here
    // --- MFMA
    #pragma unroll
    for(int kk=0;kk<2;kk++){
      const int kb = kk*64 + (lane >> 4)*16;
      s16x8 af[4];
      #pragma unroll
      for(int mi=0;mi<4;mi++){
        int row = wm*64 + mi*16 + (lane & 15);
        af[mi] = *(const s16x8*)(sAc + row*128 + (kb ^ ((row & 7) << 4)));
      }
      #pragma unroll
      for(int ni=0;ni<4;ni++){
        int row = wn*64 + ni*16 + (lane & 15);
        s16x8 bfr = *(const s16x8*)(sBc + row*128 + (kb ^ ((row & 7) << 4)));
        s16x8 b2r;
        if(DUAL) b2r = *(const s16x8*)(sB2c + row*128 + (kb ^ ((row & 7) << 4)));
        #pragma unroll
        for(int mi=0;mi<4;mi++){
          acc[mi][ni] = __builtin_amdgcn_mfma_f32_16x16x32_bf16(af[mi], bfr, acc[mi][ni], 0, 0, 0);
          if(DUAL)
            acc2[mi][ni] = __builtin_amdgcn_mfma_f32_16x16x32_bf16(af[mi], b2r, acc2[mi][ni], 0, 0, 0);
        }
      }
    }
    __syncthreads();
  }

  // --- epilogue: C/D layout col=lane&15, row=(lane>>4)*4+j  [m89-verified]
  #pragma unroll
  for(int mi=0;mi<4;mi++){
    #pragma unroll
    for(int ni=0;ni<4;ni++){
      #pragma unroll
      for(int j=0;j<4;j++){
        int s = m0 + wm*64 + mi*16 + (lane >> 4)*4 + j;
        int c = n0 + wn*64 + ni*16 + (lane & 15);
        float val;
        if(DUAL){
          float g3 = acc[mi][ni][j];
          float g1 = acc2[mi][ni][j];
          val = (g1 / (1.f + __expf(-g1))) * g3;   // silu(g1)*g3
        } else {
          val = acc[mi][ni][j];
        }
        Obase[((size_t)e*CAPACITY + s)*ldo + c] = f2bf(val);
      }
    }
  }
}

// out[t,:] = sum_k scale_k * Y[e_k, p_k, :]   (zero for dropped entries)
__global__ void gather_out(const unsigned short* __restrict__ Y,
                           const int* __restrict__ sel, const int* __restrict__ pos,
                           const float* __restrict__ scl, float* __restrict__ out){
  int t = blockIdx.x*(blockDim.x>>6) + (threadIdx.x>>6);
  int lane = threadIdx.x & 63;
  if(t >= NUM_TOKENS) return;
  float a[16];
  #pragma unroll
  for(int j=0;j<16;j++) a[j] = 0.f;
  #pragma unroll
  for(int k=0;k<TOP_K;k++){
    int i = TOP_K*t + k;
    int p = pos[i];
    if(p >= CAPACITY) continue;
    int e = sel[i];
    float sc = scl[i];
    const unsigned short* y = Y + ((size_t)e*CAPACITY + p)*HIDDEN;
    #pragma unroll
    for(int c=0;c<4;c++){
      ushort4 v = *(const ushort4*)(y + (size_t)(c*64 + lane)*4);
      a[c*4+0] += sc*bf2f(v.x);
      a[c*4+1] += sc*bf2f(v.y);
      a[c*4+2] += sc*bf2f(v.z);
      a[c*4+3] += sc*bf2f(v.w);
    }
  }
  float* o = out + (size_t)t*HIDDEN;
  #pragma unroll
  for(int c=0;c<4;c++){
    float4 v; v.x=a[c*4+0]; v.y=a[c*4+1]; v.z=a[c*4+2]; v.w=a[c*4+3];
    *(float4*)(o + (size_t)(c*64 + lane)*4) = v;
  }
}

extern "C" void kernel_launch(void* const* d_in, const int* in_sizes, int n_in,
                              void* d_out, int out_size, void* d_ws, size_t ws_size,
                              hipStream_t stream){
  const float* hs  = (const float*)d_in[0];
  const float* lg  = (const float*)d_in[1];
  const float* w31 = (const float*)d_in[2];
  const float* w2  = (const float*)d_in[3];
  float* out = (float*)d_out;

  char* ws = (char*)d_ws;
  int*   sel = (int*)(ws);
  float* scl = (float*)(ws + 32768);
  int*   pos = (int*)(ws + 65536);
  int*   cnt = (int*)(ws + 98304);
  unsigned short* Abuf = (unsigned short*)(ws + 131072);                         // 16*768*1024 bf16 = 24 MB
  unsigned short* Ibuf = (unsigned short*)(ws + 131072 + 25165824);              // 16*768*2048 bf16 = 48 MB
  unsigned short* Ybuf = (unsigned short*)(ws + 131072 + 25165824 + 50331648);   // 24 MB

  route_topk <<<NUM_TOKENS/256, 256, 0, stream>>>(lg, sel, scl);
  assign_pos <<<NUM_EXPERTS,    256, 0, stream>>>(sel, pos, cnt);
  scatter_rows<<<NFLAT/4,       256, 0, stream>>>(hs, sel, pos, Abuf);

  // GEMM1: [cnt x 1024] x [4096 x 1024]^T, dual-half + SwiGLU -> Ibuf bf16
  moe_gemm<1><<<dim3(INTER/128, CAPACITY/128, NUM_EXPERTS), 256, 49152, stream>>>(
      Abuf, HIDDEN, w31, HIDDEN, 2*INTER, Ibuf, INTER, cnt, HIDDEN);
  // GEMM2: [cnt x 2048] x [1024 x 2048]^T -> Ybuf bf16
  moe_gemm<0><<<dim3(HIDDEN/128, CAPACITY/128, NUM_EXPERTS), 256, 32768, stream>>>(
      Ibuf, INTER, w2, INTER, HIDDEN, Ybuf, HIDDEN, cnt, INTER);

  gather_out <<<NUM_TOKENS/4, 256, 0, stream>>>(Ybuf, sel, pos, scl, out);
}

// Round 3
// 842.698 us; speedup vs baseline: 1.1813x; 1.1813x over previous
//
#include <hip/hip_runtime.h>
#include <stdint.h>

#define NUM_EXPERTS 16
#define TOP_K 2
#define HIDDEN 1024
#define INTER 2048
#define NUM_TOKENS 4096
#define CAPACITY 768
#define NFLAT (NUM_TOKENS*TOP_K)

typedef __attribute__((ext_vector_type(4))) float f32x4;
typedef __attribute__((ext_vector_type(8))) short s16x8;

static __device__ __forceinline__ unsigned short f2bf(float f){
  union { float f; unsigned int u; } v; v.f = f;
  unsigned int r = (v.u + 0x7fffu + ((v.u >> 16) & 1u)) >> 16;
  return (unsigned short)r;
}
static __device__ __forceinline__ float bf2f(unsigned short s){
  union { unsigned int u; float f; } v; v.u = ((unsigned int)s) << 16;
  return v.f;
}

// ---------------------------------------------------------------- routing
// top2 softmax probs renormalized by their sum -> softmax denom cancels.
__global__ void route_topk(const float* __restrict__ logits,
                           int* __restrict__ sel, float* __restrict__ scl){
  int t = blockIdx.x*blockDim.x + threadIdx.x;
  if(t >= NUM_TOKENS) return;
  const float* L = logits + (size_t)t*NUM_EXPERTS;
  float l[NUM_EXPERTS];
  #pragma unroll
  for(int j=0;j<NUM_EXPERTS;j+=4){
    float4 v = *(const float4*)(L + j);
    l[j]=v.x; l[j+1]=v.y; l[j+2]=v.z; l[j+3]=v.w;
  }
  int i1 = 0; float m1 = l[0];
  #pragma unroll
  for(int j=1;j<NUM_EXPERTS;j++) if(l[j] > m1){ m1=l[j]; i1=j; }
  int i2 = -1; float m2 = -1e30f;
  #pragma unroll
  for(int j=0;j<NUM_EXPERTS;j++) if(j != i1 && l[j] > m2){ m2=l[j]; i2=j; }
  float e  = __expf(m2 - m1);
  float s1 = 1.f/(1.f + e);
  float s2 = e*s1;
  sel[TOP_K*t]   = i1; sel[TOP_K*t+1] = i2;
  scl[TOP_K*t]   = s1; scl[TOP_K*t+1] = s2;
}

// Exact token-order positions per expert (matches reference cumsum order).
__global__ void assign_pos(const int* __restrict__ sel,
                           int* __restrict__ pos, int* __restrict__ cnt){
  const int e = blockIdx.x;
  const int tid = threadIdx.x;
  const int lane = tid & 63, w = tid >> 6;
  __shared__ int wsum[4];
  __shared__ int carry;
  if(tid == 0) carry = 0;
  __syncthreads();
  for(int c = 0; c < NFLAT; c += 256){
    int i = c + tid;                       // NFLAT % 256 == 0
    bool flag = (sel[i] == e);
    unsigned long long mask = __ballot(flag);
    int lp   = __popcll(mask & ((1ull << lane) - 1ull));
    int wtot = __popcll(mask);
    if(lane == 0) wsum[w] = wtot;
    __syncthreads();
    int base = carry;
    int off = base;
    for(int q=0;q<w;q++) off += wsum[q];
    int tot = wsum[0] + wsum[1] + wsum[2] + wsum[3];
    if(flag) pos[i] = off + lp;
    __syncthreads();
    if(tid == 0) carry = base + tot;
  }
  if(tid == 0) cnt[e] = (carry < CAPACITY) ? carry : CAPACITY;
}

// One wave per (token,k) entry: fp32 hidden row -> bf16 row in Abuf[e][pos].
__global__ void scatter_rows(const float* __restrict__ hs,
                             const int* __restrict__ sel, const int* __restrict__ pos,
                             unsigned short* __restrict__ Abuf){
  int i = blockIdx.x*(blockDim.x>>6) + (threadIdx.x>>6);
  int lane = threadIdx.x & 63;
  if(i >= NFLAT) return;
  int p = pos[i];
  if(p >= CAPACITY) return;                 // dropped entry: contributes zero
  int e = sel[i];
  int tok = i >> 1;
  const float4* src = (const float4*)(hs + (size_t)tok*HIDDEN);
  unsigned short* dst = Abuf + ((size_t)e*CAPACITY + p)*HIDDEN;
  #pragma unroll
  for(int c=0;c<4;c++){
    float4 v = src[c*64 + lane];
    ushort4 o; o.x=f2bf(v.x); o.y=f2bf(v.y); o.z=f2bf(v.z); o.w=f2bf(v.w);
    *(ushort4*)(dst + (size_t)(c*64 + lane)*4) = o;
  }
}

// fp32 -> bf16 bulk convert (memory-bound), 32B read / 16B write per thread/iter.
__global__ void convert_w(const float* __restrict__ src,
                          unsigned short* __restrict__ dst, int n8){
  int i = blockIdx.x*blockDim.x + threadIdx.x;
  int stride = gridDim.x*blockDim.x;
  for(; i < n8; i += stride){
    const float4* s = (const float4*)(src + (size_t)i*8);
    float4 a = s[0], b = s[1];
    ushort4 o0, o1;
    o0.x=f2bf(a.x); o0.y=f2bf(a.y); o0.z=f2bf(a.z); o0.w=f2bf(a.w);
    o1.x=f2bf(b.x); o1.y=f2bf(b.y); o1.z=f2bf(b.z); o1.w=f2bf(b.w);
    ushort4* d = (ushort4*)(dst + (size_t)i*8);
    d[0]=o0; d[1]=o1;
  }
}

// ---------------------------------------------------------------- GEMM
// C[s,n] = sum_k A[s,k] * W[n,k], all bf16 inputs, fp32 acc.
// DUAL: second W half (rows + INTER) -> acc2, SwiGLU fused in epilogue.
// 128x128 tile, BK=64, 4 waves (2x2), 16x16x32 bf16 MFMA.
// A, B, B2 all staged via global_load_lds(16B) with pre-swizzled source
// addresses (linear LDS dest): LDS[row][c] = global[row][c ^ (row&7)],
// matched by XOR on ds_read -> 0 bank conflicts (verified R1).
template<int DUAL>
__global__ __launch_bounds__(256,3) void moe_gemm(
    const unsigned short* __restrict__ Abase, int lda,
    const unsigned short* __restrict__ Wbase, int ldw, int nW,
    unsigned short* __restrict__ Obase, int ldo,
    const int* __restrict__ cnts, int K)
{
  extern __shared__ char smem[];
  char* sAc  = smem;            // 16 KB  [128][64] bf16, swizzled
  char* sBc  = smem + 16384;    // 16 KB
  char* sB2c = smem + 32768;    // 16 KB (DUAL only)

  const int e   = blockIdx.z;
  const int cnt = cnts[e];
  const int m0  = blockIdx.y * 128;
  if(m0 >= cnt) return;
  const int n0  = blockIdx.x * 128;

  const int tid  = threadIdx.x;
  const int lane = tid & 63;
  const int w    = tid >> 6;
  const int wm   = w >> 1, wn = w & 1;

  const unsigned short* Aexp = Abase + (size_t)e*CAPACITY*lda;
  const unsigned short* Wexp = Wbase + (size_t)e*nW*ldw;

  f32x4 acc[4][4];
  f32x4 acc2[4][4];
  #pragma unroll
  for(int a=0;a<4;a++)
    #pragma unroll
    for(int b=0;b<4;b++){ acc[a][b]=(f32x4)(0.f); acc2[a][b]=(f32x4)(0.f); }

  // glld lane constants: 8 rows per 1KB instr; source 16B-chunk pre-swizzled
  const int ar = lane >> 3;            // row within 8-row group
  const int ac = (lane & 7) ^ ar;      // swizzled chunk index

  for(int k0 = 0; k0 < K; k0 += 64){
    #pragma unroll
    for(int q=0;q<4;q++){
      const int rowbase = w*32 + q*8;
      const unsigned short* gA = Aexp + (size_t)(m0 + rowbase + ar)*lda + k0 + ac*8;
      __builtin_amdgcn_global_load_lds(
          (const __attribute__((address_space(1))) void*)gA,
          (__attribute__((address_space(3))) void*)(sAc + rowbase*128), 16, 0, 0);
      const unsigned short* gB = Wexp + (size_t)(n0 + rowbase + ar)*ldw + k0 + ac*8;
      __builtin_amdgcn_global_load_lds(
          (const __attribute__((address_space(1))) void*)gB,
          (__attribute__((address_space(3))) void*)(sBc + rowbase*128), 16, 0, 0);
      if(DUAL){
        const unsigned short* gB2 = gB + (size_t)INTER*ldw;
        __builtin_amdgcn_global_load_lds(
            (const __attribute__((address_space(1))) void*)gB2,
            (__attribute__((address_space(3))) void*)(sB2c + rowbase*128), 16, 0, 0);
      }
    }
    __syncthreads();   // drains vmcnt(0): tiles ready
    #pragma unroll
    for(int kk=0;kk<2;kk++){
      const int kb = kk*64 + (lane >> 4)*16;
      s16x8 af[4];
      #pragma unroll
      for(int mi=0;mi<4;mi++){
        int row = wm*64 + mi*16 + (lane & 15);
        af[mi] = *(const s16x8*)(sAc + row*128 + (kb ^ ((row & 7) << 4)));
      }
      #pragma unroll
      for(int ni=0;ni<4;ni++){
        int row = wn*64 + ni*16 + (lane & 15);
        s16x8 bfr = *(const s16x8*)(sBc + row*128 + (kb ^ ((row & 7) << 4)));
        s16x8 b2r;
        if(DUAL) b2r = *(const s16x8*)(sB2c + row*128 + (kb ^ ((row & 7) << 4)));
        #pragma unroll
        for(int mi=0;mi<4;mi++){
          acc[mi][ni] = __builtin_amdgcn_mfma_f32_16x16x32_bf16(af[mi], bfr, acc[mi][ni], 0, 0, 0);
          if(DUAL)
            acc2[mi][ni] = __builtin_amdgcn_mfma_f32_16x16x32_bf16(af[mi], b2r, acc2[mi][ni], 0, 0, 0);
        }
      }
    }
    __syncthreads();
  }

  // epilogue: C/D layout col=lane&15, row=(lane>>4)*4+j
  #pragma unroll
  for(int mi=0;mi<4;mi++){
    #pragma unroll
    for(int ni=0;ni<4;ni++){
      #pragma unroll
      for(int j=0;j<4;j++){
        int s = m0 + wm*64 + mi*16 + (lane >> 4)*4 + j;
        int c = n0 + wn*64 + ni*16 + (lane & 15);
        float val;
        if(DUAL){
          float g3 = acc[mi][ni][j];
          float g1 = acc2[mi][ni][j];
          val = (g1 / (1.f + __expf(-g1))) * g3;   // silu(g1)*g3
        } else {
          val = acc[mi][ni][j];
        }
        Obase[((size_t)e*CAPACITY + s)*ldo + c] = f2bf(val);
      }
    }
  }
}

// out[t,:] = sum_k scale_k * Y[e_k, p_k, :]
__global__ void gather_out(const unsigned short* __restrict__ Y,
                           const int* __restrict__ sel, const int* __restrict__ pos,
                           const float* __restrict__ scl, float* __restrict__ out){
  int t = blockIdx.x*(blockDim.x>>6) + (threadIdx.x>>6);
  int lane = threadIdx.x & 63;
  if(t >= NUM_TOKENS) return;
  float a[16];
  #pragma unroll
  for(int j=0;j<16;j++) a[j] = 0.f;
  #pragma unroll
  for(int k=0;k<TOP_K;k++){
    int i = TOP_K*t + k;
    int p = pos[i];
    if(p >= CAPACITY) continue;
    int e = sel[i];
    float sc = scl[i];
    const unsigned short* y = Y + ((size_t)e*CAPACITY + p)*HIDDEN;
    #pragma unroll
    for(int c=0;c<4;c++){
      ushort4 v = *(const ushort4*)(y + (size_t)(c*64 + lane)*4);
      a[c*4+0] += sc*bf2f(v.x);
      a[c*4+1] += sc*bf2f(v.y);
      a[c*4+2] += sc*bf2f(v.z);
      a[c*4+3] += sc*bf2f(v.w);
    }
  }
  float* o = out + (size_t)t*HIDDEN;
  #pragma unroll
  for(int c=0;c<4;c++){
    float4 v; v.x=a[c*4+0]; v.y=a[c*4+1]; v.z=a[c*4+2]; v.w=a[c*4+3];
    *(float4*)(o + (size_t)(c*64 + lane)*4) = v;
  }
}

extern "C" void kernel_launch(void* const* d_in, const int* in_sizes, int n_in,
                              void* d_out, int out_size, void* d_ws, size_t ws_size,
                              hipStream_t stream){
  const float* hs  = (const float*)d_in[0];
  const float* lg  = (const float*)d_in[1];
  const float* w31 = (const float*)d_in[2];
  const float* w2  = (const float*)d_in[3];
  float* out = (float*)d_out;

  char* ws = (char*)d_ws;
  int*   sel = (int*)(ws);
  float* scl = (float*)(ws + 32768);
  int*   pos = (int*)(ws + 65536);
  int*   cnt = (int*)(ws + 98304);
  // Abuf 24MB | Ibuf 48MB | big region 128MB:
  //   big holds Wbuf1(128MB bf16 w31) during GEMM1;
  //   after GEMM1: Wbuf2(64MB bf16 w2) at big, Ybuf(24MB) at big+64MB.
  unsigned short* Abuf  = (unsigned short*)(ws + 131072);
  unsigned short* Ibuf  = (unsigned short*)(ws + 131072 + 25165824);
  char*           big   = ws + 131072 + 25165824 + 50331648;
  unsigned short* Wbuf1 = (unsigned short*)big;
  unsigned short* Wbuf2 = (unsigned short*)big;
  unsigned short* Ybuf  = (unsigned short*)(big + 67108864);

  route_topk <<<NUM_TOKENS/256, 256, 0, stream>>>(lg, sel, scl);
  assign_pos <<<NUM_EXPERTS,    256, 0, stream>>>(sel, pos, cnt);
  scatter_rows<<<NFLAT/4,       256, 0, stream>>>(hs, sel, pos, Abuf);

  convert_w<<<2048, 256, 0, stream>>>(w31, Wbuf1, NUM_EXPERTS*2*INTER*HIDDEN/8);

  // GEMM1: [cnt x 1024] x [4096 x 1024]^T dual-half + SwiGLU -> Ibuf bf16
  moe_gemm<1><<<dim3(INTER/128, CAPACITY/128, NUM_EXPERTS), 256, 49152, stream>>>(
      Abuf, HIDDEN, Wbuf1, HIDDEN, 2*INTER, Ibuf, INTER, cnt, HIDDEN);

  convert_w<<<2048, 256, 0, stream>>>(w2, Wbuf2, NUM_EXPERTS*HIDDEN*INTER/8);

  // GEMM2: [cnt x 2048] x [1024 x 2048]^T -> Ybuf bf16
  moe_gemm<0><<<dim3(HIDDEN/128, CAPACITY/128, NUM_EXPERTS), 256, 32768, stream>>>(
      Ibuf, INTER, Wbuf2, INTER, HIDDEN, Ybuf, HIDDEN, cnt, INTER);

  gather_out <<<NUM_TOKENS/4, 256, 0, stream>>>(Ybuf, sel, pos, scl, out);
}